// Round 14
// baseline (100.195 us; speedup 1.0000x reference)
//
#include <hip/hip_runtime.h>
#include <hip/hip_bf16.h>
#include <hip/hip_fp16.h>

#define N_NODES 100000
#define N_EDGES 1600000
#define HEADS 8
#define NH (N_NODES * HEADS)    // 800000
#define ALPHA 0.2f

#define BSHIFT 7
#define BSIZE 128               // dst nodes per bucket
#define NBUCK 782               // ceil(100000 / 128)
#define EPB 4096                // edges per hist/scatter block
#define NEB 391                 // ceil(1600000 / 4096)
#define GPROJ 782               // ceil(800000 / 1024) proj blocks (1024 thr)
#define CAP 3072                // per-chunk record capacity (mean 2046, +22 sigma)
#define RPT 6                   // CAP / 512 records per thread

typedef float floatx4 __attribute__((ext_vector_type(4)));

__device__ __forceinline__ float lrelu(float s) {
    return s >= 0.0f ? s : ALPHA * s;
}

// bf16 helpers (rd needs fp32 EXPONENT range: denom ~1e7 -> rd ~1e-7, which
// underflows fp16 subnormals -- the R12 failure -- but is a normal bf16).
__device__ __forceinline__ unsigned short f2bf(float f) {
    unsigned u = __float_as_uint(f);
    u += 0x7FFFu + ((u >> 16) & 1u);      // round-to-nearest-even
    return (unsigned short)(u >> 16);
}
__device__ __forceinline__ float bf2f(unsigned short s) {
    return __uint_as_float((unsigned)s << 16);
}

// Tables:
//   p1h[n*8+h]  : fp16 src-projection (range +-~16: fp16-safe)
//   prh[n*16+*] : 32-byte record = {fp16 p2[8] | bf16 rd[8]} -- one 32 B
//                 granule serves BOTH dst-indexed gathers in norm.
// No memset anywhere: hist writes per-block count vectors (plain stores),
// scan reduces them. (R13: the 3 KB hipMemsetAsync became a ~40 us
// fillBufferAligned graph node.)

// Kernel 1 (fused): blocks [0, GPROJ) compute per-node projections;
// blocks [GPROJ, GPROJ+NEB) write per-block dst-bucket histograms.
__global__ __launch_bounds__(1024) void proj_hist_kernel(
        const float* __restrict__ x, const float* __restrict__ a,
        const int* __restrict__ edge,
        __half* __restrict__ p1h, __half* __restrict__ prh,
        unsigned* __restrict__ hcnt) {
    __shared__ unsigned lh[NBUCK];
    int tid = threadIdx.x;
    if (blockIdx.x < GPROJ) {
        int t = blockIdx.x * 1024 + tid;
        if (t >= NH) return;
        int hd = t & 7;
        int n  = t >> 3;
        const float4* xp  = (const float4*)(x + (size_t)n * 128 + hd * 16);
        const float4* a1p = (const float4*)(a);
        const float4* a2p = (const float4*)(a + 16);
        float s1 = 0.f, s2 = 0.f;
#pragma unroll
        for (int i = 0; i < 4; ++i) {
            float4 xv = xp[i];
            float4 v1 = a1p[i];
            float4 v2 = a2p[i];
            s1 += xv.x * v1.x + xv.y * v1.y + xv.z * v1.z + xv.w * v1.w;
            s2 += xv.x * v2.x + xv.y * v2.y + xv.z * v2.z + xv.w * v2.w;
        }
        p1h[t] = __float2half_rn(s1);
        prh[(size_t)n * 16 + hd] = __float2half_rn(s2);
    } else {
        int blk = blockIdx.x - GPROJ;
        for (int i = tid; i < NBUCK; i += 1024) lh[i] = 0;
        __syncthreads();
        int base = blk * EPB;
#pragma unroll
        for (int k = 0; k < EPB / 1024; ++k) {
            int e = base + k * 1024 + tid;
            if (e < N_EDGES) atomicAdd(&lh[(unsigned)edge[N_EDGES + e] >> BSHIFT], 1u);
        }
        __syncthreads();
        for (int i = tid; i < NBUCK; i += 1024)
            hcnt[(size_t)blk * NBUCK + i] = lh[i];       // plain store, no init
    }
}

// Kernel 2: reduce per-block histograms, then exclusive scan (single block).
__global__ __launch_bounds__(1024) void scan_kernel(const unsigned* __restrict__ hcnt,
                                                    unsigned* __restrict__ goff,
                                                    unsigned* __restrict__ gcur) {
    __shared__ unsigned s[1024];
    int t = threadIdx.x;
    unsigned v = 0;
    if (t < NBUCK) {
        for (int j = 0; j < NEB; ++j)
            v += hcnt[(size_t)j * NBUCK + t];            // coalesced across t
    }
    s[t] = v;
    __syncthreads();
    for (int d = 1; d < 1024; d <<= 1) {
        unsigned add = (t >= d) ? s[t - d] : 0u;
        __syncthreads();
        s[t] += add;
        __syncthreads();
    }
    if (t < NBUCK) {
        unsigned excl = s[t] - v;
        goff[t] = excl;
        gcur[t] = excl;
    }
    if (t == 0) goff[NBUCK] = N_EDGES;
}

// Kernel 3: scatter 4-byte records (src<<7 | dst_local) into bucket order.
__global__ __launch_bounds__(1024) void scatter_kernel(const int* __restrict__ edge,
                                                       unsigned* __restrict__ gcur,
                                                       unsigned* __restrict__ sorted) {
    __shared__ int lsrc[EPB];
    __shared__ int ldst[EPB];
    __shared__ unsigned lh[NBUCK];
    __shared__ unsigned lbase[NBUCK];
    int t = threadIdx.x;
    int base = blockIdx.x * EPB;
    for (int i = t; i < NBUCK; i += 1024) lh[i] = 0;
    __syncthreads();
#pragma unroll
    for (int k = 0; k < EPB / 1024; ++k) {
        int i = k * 1024 + t, e = base + i;
        if (e < N_EDGES) {
            lsrc[i] = edge[e];
            int d = edge[N_EDGES + e];
            ldst[i] = d;
            atomicAdd(&lh[(unsigned)d >> BSHIFT], 1u);
        }
    }
    __syncthreads();
    for (int i = t; i < NBUCK; i += 1024) {
        unsigned c = lh[i];
        lbase[i] = c ? atomicAdd(&gcur[i], c) : 0u;
        lh[i] = 0;   // reuse as local cursor
    }
    __syncthreads();
#pragma unroll
    for (int k = 0; k < EPB / 1024; ++k) {
        int i = k * 1024 + t, e = base + i;
        if (e < N_EDGES) {
            int d = ldst[i];
            unsigned b = (unsigned)d >> BSHIFT;
            unsigned pos = lbase[b] + atomicAdd(&lh[b], 1u);
            sorted[pos] = ((unsigned)lsrc[i] << BSHIFT) | (unsigned)(d & (BSIZE - 1));
        }
    }
}

// Kernel 4: one block per bucket, no float atomics. Counting-sort the bucket's
// records by dst_local in LDS; each thread owns (dl, head-pair) and serially
// accumulates its dst's edges in fp32 registers. Writes bf16 reciprocal
// denominators into the rd-half of prh.
__global__ __launch_bounds__(512) void denom_kernel(const unsigned* __restrict__ sorted,
                                                    const unsigned* __restrict__ goff,
                                                    const __half* __restrict__ p1h,
                                                    __half* __restrict__ prh) {
    __shared__ unsigned lsrc[CAP];     // 12 KB sorted-by-dl src indices
    __shared__ unsigned lh[BSIZE];     // per-dl count
    __shared__ unsigned lst[BSIZE];    // per-dl start
    __shared__ unsigned lcur[BSIZE];   // per-dl cursor
    __shared__ unsigned lscan[BSIZE];  // scan temp
    int t = threadIdx.x;
    int b = blockIdx.x;
    int dl = t >> 2;                   // 0..127: owned dst-local
    int hp = t & 3;                    // 0..3: owned head pair (2*hp, 2*hp+1)
    size_t node = (size_t)b * BSIZE + dl;
    bool valid = node < N_NODES;
    float p2a = 0.f, p2b = 0.f;
    if (valid) {
        float2 pv = __half22float2(*(const __half2*)(prh + node * 16 + hp * 2));
        p2a = pv.x; p2b = pv.y;
    }
    float acc0 = 0.f, acc1 = 0.f;
    unsigned s0 = goff[b], s1 = goff[b + 1];

    for (unsigned cs = s0; cs < s1; cs += CAP) {
        unsigned cnt = min((unsigned)CAP, s1 - cs);
        if (t < BSIZE) lh[t] = 0;
        __syncthreads();
        unsigned recs[RPT];
#pragma unroll
        for (int k = 0; k < RPT; ++k) {
            unsigned i = (unsigned)t + (unsigned)k * 512u;
            bool v = i < cnt;
            recs[k] = v ? sorted[cs + i] : 0xFFFFFFFFu;
            if (v) atomicAdd(&lh[recs[k] & (BSIZE - 1)], 1u);
        }
        __syncthreads();
        if (t < BSIZE) lscan[t] = lh[t];
        __syncthreads();
        for (int d = 1; d < BSIZE; d <<= 1) {
            unsigned v = 0;
            if (t < BSIZE && t >= d) v = lscan[t - d];
            __syncthreads();
            if (t < BSIZE) lscan[t] += v;
            __syncthreads();
        }
        if (t < BSIZE) {
            unsigned st = lscan[t] - lh[t];
            lst[t] = st;
            lcur[t] = st;
        }
        __syncthreads();
#pragma unroll
        for (int k = 0; k < RPT; ++k) {
            unsigned r = recs[k];
            if (r != 0xFFFFFFFFu) {
                unsigned d = r & (BSIZE - 1);
                unsigned pos = atomicAdd(&lcur[d], 1u);
                lsrc[pos] = r >> BSHIFT;
            }
        }
        __syncthreads();
        unsigned e0 = lst[dl], e1 = lst[dl] + lh[dl];
        for (unsigned k = e0; k < e1; ++k) {
            unsigned src = lsrc[k];                       // broadcast to 4 lanes
            float2 pv = __half22float2(*(const __half2*)(p1h + (size_t)src * 8 + hp * 2));
            acc0 += __expf(lrelu(pv.x + p2a));
            acc1 += __expf(lrelu(pv.y + p2b));
        }
        __syncthreads();   // protect lh/lst before next chunk
    }
    if (valid) {
        unsigned short r0 = f2bf(1.0f / (acc0 + 1e-16f));
        unsigned short r1 = f2bf(1.0f / (acc1 + 1e-16f));
        // rd-half of prh (4-byte aligned: byte offset node*32 + 16 + hp*4)
        *(unsigned*)((unsigned short*)prh + node * 16 + 8 + hp * 2) =
            ((unsigned)r1 << 16) | r0;
    }
}

// Kernel 5: edges in ORIGINAL order -> coalesced edge reads and out writes.
// Per edge: p1h[src] (16 B fp16) + prh[dst] (32 B, fp16 p2 + bf16 rd).
// Non-temporal full-line out stores.
__global__ __launch_bounds__(256) void norm_kernel(const int* __restrict__ edge,
                                                   const __half* __restrict__ p1h,
                                                   const __half* __restrict__ prh,
                                                   float* __restrict__ out) {
    int e = blockIdx.x * 256 + threadIdx.x;
    if (e >= N_EDGES) return;
    int src = edge[e];
    int dst = edge[N_EDGES + e];
    float4 pv = *(const float4*)(p1h + (size_t)src * 8);       // 8 fp16 p1
    float4 qa = *(const float4*)(prh + (size_t)dst * 16);      // 8 fp16 p2
    float4 qb = *(const float4*)(prh + (size_t)dst * 16 + 8);  // 8 bf16 rd
    const __half2* s1p = (const __half2*)&pv;
    const __half2* s2p = (const __half2*)&qa;
    const unsigned short* rdu = (const unsigned short*)&qb;
    floatx4 o0, o1;
    float ov[8];
#pragma unroll
    for (int k = 0; k < 4; ++k) {
        float2 f1 = __half22float2(s1p[k]);
        float2 f2 = __half22float2(s2p[k]);
        ov[2 * k]     = __expf(lrelu(f1.x + f2.x)) * bf2f(rdu[2 * k]);
        ov[2 * k + 1] = __expf(lrelu(f1.y + f2.y)) * bf2f(rdu[2 * k + 1]);
    }
    o0.x = ov[0]; o0.y = ov[1]; o0.z = ov[2]; o0.w = ov[3];
    o1.x = ov[4]; o1.y = ov[5]; o1.z = ov[6]; o1.w = ov[7];
    floatx4* op = (floatx4*)(out + (size_t)e * 8);
    __builtin_nontemporal_store(o0, op);
    __builtin_nontemporal_store(o1, op + 1);
}

extern "C" void kernel_launch(void* const* d_in, const int* in_sizes, int n_in,
                              void* d_out, int out_size, void* d_ws, size_t ws_size,
                              hipStream_t stream) {
    const float* x    = (const float*)d_in[0];
    const float* a    = (const float*)d_in[1];
    const int*   edge = (const int*)d_in[2];
    float* out = (float*)d_out;

    // Workspace layout (~12.4 MB):
    unsigned* sorted = (unsigned*)d_ws;                              // 6.4 MB
    __half*   p1h    = (__half*)(sorted + N_EDGES);                  // 1.6 MB
    __half*   prh    = p1h + NH;                                     // 3.2 MB (p2+rd)
    unsigned* hcnt   = (unsigned*)(prh + (size_t)N_NODES * 16);      // 1.22 MB
    unsigned* goff   = hcnt + (size_t)NEB * NBUCK;                   // 783
    unsigned* gcur   = goff + NBUCK + 1;                             // 782

    proj_hist_kernel<<<GPROJ + NEB, 1024, 0, stream>>>(x, a, edge, p1h, prh, hcnt);
    scan_kernel<<<1, 1024, 0, stream>>>(hcnt, goff, gcur);
    scatter_kernel<<<NEB, 1024, 0, stream>>>(edge, gcur, sorted);
    denom_kernel<<<NBUCK, 512, 0, stream>>>(sorted, goff, p1h, prh);
    norm_kernel<<<(N_EDGES + 255) / 256, 256, 0, stream>>>(edge, p1h, prh, out);
}

// Round 15
// 96.561 us; speedup vs baseline: 1.0376x; 1.0376x over previous
//
#include <hip/hip_runtime.h>
#include <hip/hip_bf16.h>
#include <hip/hip_fp16.h>

#define N_NODES 100000
#define N_EDGES 1600000
#define HEADS 8
#define NH (N_NODES * HEADS)    // 800000
#define ALPHA 0.2f

#define BSHIFT 7
#define BSIZE 128               // dst nodes per bucket
#define NBUCK 782               // ceil(100000 / 128)
#define EPB 4096                // edges per hist/scatter block
#define NEB 391                 // ceil(1600000 / 4096)
#define GPROJ 782               // ceil(800000 / 1024) proj blocks (1024 thr)
#define CAP 3072                // per-chunk record capacity (mean 2046, +22 sigma)
#define RPT 6                   // CAP / 512 records per thread

typedef float floatx4 __attribute__((ext_vector_type(4)));

__device__ __forceinline__ float lrelu(float s) {
    return s >= 0.0f ? s : ALPHA * s;
}

// bf16 helpers (rd needs fp32 EXPONENT range: denom ~1e7 -> rd ~1e-7, which
// underflows fp16 subnormals -- the R12 failure -- but is a normal bf16).
__device__ __forceinline__ unsigned short f2bf(float f) {
    unsigned u = __float_as_uint(f);
    u += 0x7FFFu + ((u >> 16) & 1u);      // round-to-nearest-even
    return (unsigned short)(u >> 16);
}
__device__ __forceinline__ float bf2f(unsigned short s) {
    return __uint_as_float((unsigned)s << 16);
}

// Tables:
//   p1h[n*8+h]  : fp16 src-projection (range +-~16: fp16-safe)
//   prh[n*16+*] : 32-byte record = {fp16 p2[8] | bf16 rd[8]} -- one 32 B
//                 granule serves BOTH dst-indexed gathers in norm.
// denom accumulates from the SAME quantized p1/p2 that norm reads, so the
// softmax is self-consistent under quantization.
// (R14 lesson: the 40us fillBufferAligned rows in rocprof are the HARNESS's
// 256 MiB workspace poisons + counter-replay artifacts, not our 3 KB memset;
// the hcnt/no-memset variant benched 3.3us SLOWER. This is the R13 structure.)

// Kernel 1 (fused): blocks [0, GPROJ) compute per-node projections;
// blocks [GPROJ, GPROJ+NEB) histogram dst buckets.
__global__ __launch_bounds__(1024) void proj_hist_kernel(
        const float* __restrict__ x, const float* __restrict__ a,
        const int* __restrict__ edge,
        __half* __restrict__ p1h, __half* __restrict__ prh,
        unsigned* __restrict__ gcount) {
    __shared__ unsigned lh[NBUCK];
    int tid = threadIdx.x;
    if (blockIdx.x < GPROJ) {
        int t = blockIdx.x * 1024 + tid;
        if (t >= NH) return;
        int hd = t & 7;
        int n  = t >> 3;
        const float4* xp  = (const float4*)(x + (size_t)n * 128 + hd * 16);
        const float4* a1p = (const float4*)(a);
        const float4* a2p = (const float4*)(a + 16);
        float s1 = 0.f, s2 = 0.f;
#pragma unroll
        for (int i = 0; i < 4; ++i) {
            float4 xv = xp[i];
            float4 v1 = a1p[i];
            float4 v2 = a2p[i];
            s1 += xv.x * v1.x + xv.y * v1.y + xv.z * v1.z + xv.w * v1.w;
            s2 += xv.x * v2.x + xv.y * v2.y + xv.z * v2.z + xv.w * v2.w;
        }
        p1h[t] = __float2half_rn(s1);
        prh[(size_t)n * 16 + hd] = __float2half_rn(s2);
    } else {
        for (int i = tid; i < NBUCK; i += 1024) lh[i] = 0;
        __syncthreads();
        int base = (blockIdx.x - GPROJ) * EPB;
#pragma unroll
        for (int k = 0; k < EPB / 1024; ++k) {
            int e = base + k * 1024 + tid;
            if (e < N_EDGES) atomicAdd(&lh[(unsigned)edge[N_EDGES + e] >> BSHIFT], 1u);
        }
        __syncthreads();
        for (int i = tid; i < NBUCK; i += 1024)
            if (lh[i]) atomicAdd(&gcount[i], lh[i]);
    }
}

// Kernel 2: exclusive scan of 782 bucket counts (single block).
__global__ __launch_bounds__(1024) void scan_kernel(const unsigned* __restrict__ gcount,
                                                    unsigned* __restrict__ goff,
                                                    unsigned* __restrict__ gcur) {
    __shared__ unsigned s[1024];
    int t = threadIdx.x;
    unsigned v = (t < NBUCK) ? gcount[t] : 0u;
    s[t] = v;
    __syncthreads();
    for (int d = 1; d < 1024; d <<= 1) {
        unsigned add = (t >= d) ? s[t - d] : 0u;
        __syncthreads();
        s[t] += add;
        __syncthreads();
    }
    if (t < NBUCK) {
        unsigned excl = s[t] - v;
        goff[t] = excl;
        gcur[t] = excl;
    }
    if (t == 0) goff[NBUCK] = N_EDGES;
}

// Kernel 3: scatter 4-byte records (src<<7 | dst_local) into bucket order.
__global__ __launch_bounds__(1024) void scatter_kernel(const int* __restrict__ edge,
                                                       unsigned* __restrict__ gcur,
                                                       unsigned* __restrict__ sorted) {
    __shared__ int lsrc[EPB];
    __shared__ int ldst[EPB];
    __shared__ unsigned lh[NBUCK];
    __shared__ unsigned lbase[NBUCK];
    int t = threadIdx.x;
    int base = blockIdx.x * EPB;
    for (int i = t; i < NBUCK; i += 1024) lh[i] = 0;
    __syncthreads();
#pragma unroll
    for (int k = 0; k < EPB / 1024; ++k) {
        int i = k * 1024 + t, e = base + i;
        if (e < N_EDGES) {
            lsrc[i] = edge[e];
            int d = edge[N_EDGES + e];
            ldst[i] = d;
            atomicAdd(&lh[(unsigned)d >> BSHIFT], 1u);
        }
    }
    __syncthreads();
    for (int i = t; i < NBUCK; i += 1024) {
        unsigned c = lh[i];
        lbase[i] = c ? atomicAdd(&gcur[i], c) : 0u;
        lh[i] = 0;   // reuse as local cursor
    }
    __syncthreads();
#pragma unroll
    for (int k = 0; k < EPB / 1024; ++k) {
        int i = k * 1024 + t, e = base + i;
        if (e < N_EDGES) {
            int d = ldst[i];
            unsigned b = (unsigned)d >> BSHIFT;
            unsigned pos = lbase[b] + atomicAdd(&lh[b], 1u);
            sorted[pos] = ((unsigned)lsrc[i] << BSHIFT) | (unsigned)(d & (BSIZE - 1));
        }
    }
}

// Kernel 4: one block per bucket, no float atomics. Counting-sort the bucket's
// records by dst_local in LDS; each thread owns (dl, head-pair) and serially
// accumulates its dst's edges in fp32 registers. Writes bf16 reciprocal
// denominators into the rd-half of prh.
__global__ __launch_bounds__(512) void denom_kernel(const unsigned* __restrict__ sorted,
                                                    const unsigned* __restrict__ goff,
                                                    const __half* __restrict__ p1h,
                                                    __half* __restrict__ prh) {
    __shared__ unsigned lsrc[CAP];     // 12 KB sorted-by-dl src indices
    __shared__ unsigned lh[BSIZE];     // per-dl count
    __shared__ unsigned lst[BSIZE];    // per-dl start
    __shared__ unsigned lcur[BSIZE];   // per-dl cursor
    __shared__ unsigned lscan[BSIZE];  // scan temp
    int t = threadIdx.x;
    int b = blockIdx.x;
    int dl = t >> 2;                   // 0..127: owned dst-local
    int hp = t & 3;                    // 0..3: owned head pair (2*hp, 2*hp+1)
    size_t node = (size_t)b * BSIZE + dl;
    bool valid = node < N_NODES;
    float p2a = 0.f, p2b = 0.f;
    if (valid) {
        float2 pv = __half22float2(*(const __half2*)(prh + node * 16 + hp * 2));
        p2a = pv.x; p2b = pv.y;
    }
    float acc0 = 0.f, acc1 = 0.f;
    unsigned s0 = goff[b], s1 = goff[b + 1];

    for (unsigned cs = s0; cs < s1; cs += CAP) {
        unsigned cnt = min((unsigned)CAP, s1 - cs);
        if (t < BSIZE) lh[t] = 0;
        __syncthreads();
        unsigned recs[RPT];
#pragma unroll
        for (int k = 0; k < RPT; ++k) {
            unsigned i = (unsigned)t + (unsigned)k * 512u;
            bool v = i < cnt;
            recs[k] = v ? sorted[cs + i] : 0xFFFFFFFFu;
            if (v) atomicAdd(&lh[recs[k] & (BSIZE - 1)], 1u);
        }
        __syncthreads();
        if (t < BSIZE) lscan[t] = lh[t];
        __syncthreads();
        for (int d = 1; d < BSIZE; d <<= 1) {
            unsigned v = 0;
            if (t < BSIZE && t >= d) v = lscan[t - d];
            __syncthreads();
            if (t < BSIZE) lscan[t] += v;
            __syncthreads();
        }
        if (t < BSIZE) {
            unsigned st = lscan[t] - lh[t];
            lst[t] = st;
            lcur[t] = st;
        }
        __syncthreads();
#pragma unroll
        for (int k = 0; k < RPT; ++k) {
            unsigned r = recs[k];
            if (r != 0xFFFFFFFFu) {
                unsigned d = r & (BSIZE - 1);
                unsigned pos = atomicAdd(&lcur[d], 1u);
                lsrc[pos] = r >> BSHIFT;
            }
        }
        __syncthreads();
        unsigned e0 = lst[dl], e1 = lst[dl] + lh[dl];
        for (unsigned k = e0; k < e1; ++k) {
            unsigned src = lsrc[k];                       // broadcast to 4 lanes
            float2 pv = __half22float2(*(const __half2*)(p1h + (size_t)src * 8 + hp * 2));
            acc0 += __expf(lrelu(pv.x + p2a));
            acc1 += __expf(lrelu(pv.y + p2b));
        }
        __syncthreads();   // protect lh/lst before next chunk
    }
    if (valid) {
        unsigned short r0 = f2bf(1.0f / (acc0 + 1e-16f));
        unsigned short r1 = f2bf(1.0f / (acc1 + 1e-16f));
        // rd-half of prh (4-byte aligned: byte offset node*32 + 16 + hp*4)
        *(unsigned*)((unsigned short*)prh + node * 16 + 8 + hp * 2) =
            ((unsigned)r1 << 16) | r0;
    }
}

// Kernel 5: edges in ORIGINAL order -> coalesced edge reads and out writes.
// Per edge: p1h[src] (16 B fp16) + prh[dst] (32 B, fp16 p2 + bf16 rd).
// Grid is exactly 6250 blocks (1.6M/256): no bounds check.
__global__ __launch_bounds__(256) void norm_kernel(const int* __restrict__ edge,
                                                   const __half* __restrict__ p1h,
                                                   const __half* __restrict__ prh,
                                                   float* __restrict__ out) {
    int e = blockIdx.x * 256 + threadIdx.x;
    int src = edge[e];
    int dst = edge[N_EDGES + e];
    float4 pv = *(const float4*)(p1h + (size_t)src * 8);       // 8 fp16 p1
    float4 qa = *(const float4*)(prh + (size_t)dst * 16);      // 8 fp16 p2
    float4 qb = *(const float4*)(prh + (size_t)dst * 16 + 8);  // 8 bf16 rd
    const __half2* s1p = (const __half2*)&pv;
    const __half2* s2p = (const __half2*)&qa;
    const unsigned short* rdu = (const unsigned short*)&qb;
    floatx4 o0, o1;
    float ov[8];
#pragma unroll
    for (int k = 0; k < 4; ++k) {
        float2 f1 = __half22float2(s1p[k]);
        float2 f2 = __half22float2(s2p[k]);
        ov[2 * k]     = __expf(lrelu(f1.x + f2.x)) * bf2f(rdu[2 * k]);
        ov[2 * k + 1] = __expf(lrelu(f1.y + f2.y)) * bf2f(rdu[2 * k + 1]);
    }
    o0.x = ov[0]; o0.y = ov[1]; o0.z = ov[2]; o0.w = ov[3];
    o1.x = ov[4]; o1.y = ov[5]; o1.z = ov[6]; o1.w = ov[7];
    floatx4* op = (floatx4*)(out + (size_t)e * 8);
    __builtin_nontemporal_store(o0, op);
    __builtin_nontemporal_store(o1, op + 1);
}

extern "C" void kernel_launch(void* const* d_in, const int* in_sizes, int n_in,
                              void* d_out, int out_size, void* d_ws, size_t ws_size,
                              hipStream_t stream) {
    const float* x    = (const float*)d_in[0];
    const float* a    = (const float*)d_in[1];
    const int*   edge = (const int*)d_in[2];
    float* out = (float*)d_out;

    // Workspace layout (~11.2 MB):
    unsigned* sorted = (unsigned*)d_ws;                              // 6.4 MB
    __half*   p1h    = (__half*)(sorted + N_EDGES);                  // 1.6 MB
    __half*   prh    = p1h + NH;                                     // 3.2 MB (p2+rd)
    unsigned* gcount = (unsigned*)(prh + (size_t)N_NODES * 16);      // 782
    unsigned* goff   = gcount + NBUCK;                               // 783
    unsigned* gcur   = goff + NBUCK + 1;                             // 782

    (void)hipMemsetAsync(gcount, 0, NBUCK * sizeof(unsigned), stream);

    proj_hist_kernel<<<GPROJ + NEB, 1024, 0, stream>>>(x, a, edge, p1h, prh, gcount);
    scan_kernel<<<1, 1024, 0, stream>>>(gcount, goff, gcur);
    scatter_kernel<<<NEB, 1024, 0, stream>>>(edge, gcur, sorted);
    denom_kernel<<<NBUCK, 512, 0, stream>>>(sorted, goff, p1h, prh);
    norm_kernel<<<N_EDGES / 256, 256, 0, stream>>>(edge, p1h, prh, out);
}

// Round 16
// 93.699 us; speedup vs baseline: 1.0693x; 1.0305x over previous
//
#include <hip/hip_runtime.h>
#include <hip/hip_bf16.h>
#include <hip/hip_fp16.h>

#define N_NODES 100000
#define N_EDGES 1600000
#define HEADS 8
#define NH (N_NODES * HEADS)    // 800000
#define ALPHA 0.2f

#define BSHIFT 7
#define BSIZE 128               // dst nodes per bucket
#define NBUCK 782               // ceil(100000 / 128)
#define EPB 4096                // edges per hist/scatter block
#define NEB 391                 // ceil(1600000 / 4096)
#define GPROJ 782               // ceil(800000 / 1024) proj blocks (1024 thr)
#define CAP 3072                // per-chunk record capacity (mean 2046, +22 sigma)
#define RPT 6                   // CAP / 512 records per thread

typedef float floatx4 __attribute__((ext_vector_type(4)));

__device__ __forceinline__ float lrelu(float s) {
    return s >= 0.0f ? s : ALPHA * s;
}

// bf16 helpers (rd needs fp32 EXPONENT range: denom ~1e7 -> rd ~1e-7, which
// underflows fp16 subnormals -- the R12 failure -- but is a normal bf16).
__device__ __forceinline__ unsigned short f2bf(float f) {
    unsigned u = __float_as_uint(f);
    u += 0x7FFFu + ((u >> 16) & 1u);      // round-to-nearest-even
    return (unsigned short)(u >> 16);
}
__device__ __forceinline__ float bf2f(unsigned short s) {
    return __uint_as_float((unsigned)s << 16);
}

// Tables:
//   p1h[n*8+h]  : fp16 src-projection (range +-~16: fp16-safe)
//   prh[n*16+*] : 32-byte record = {fp16 p2[8] | bf16 rd[8]} -- one 32 B
//                 granule serves BOTH dst-indexed gathers in norm.
// R16: scan_kernel removed -- each scatter block recomputes the 782-entry
// exclusive scan in LDS (3 KB broadcast read, overlapped), block 0 publishes
// goff for denom; gcur starts at 0 (memset) and scatter adds its local base.

// Kernel 1 (fused): blocks [0, GPROJ) compute per-node projections;
// blocks [GPROJ, GPROJ+NEB) histogram dst buckets.
__global__ __launch_bounds__(1024) void proj_hist_kernel(
        const float* __restrict__ x, const float* __restrict__ a,
        const int* __restrict__ edge,
        __half* __restrict__ p1h, __half* __restrict__ prh,
        unsigned* __restrict__ gcount) {
    __shared__ unsigned lh[NBUCK];
    int tid = threadIdx.x;
    if (blockIdx.x < GPROJ) {
        int t = blockIdx.x * 1024 + tid;
        if (t >= NH) return;
        int hd = t & 7;
        int n  = t >> 3;
        const float4* xp  = (const float4*)(x + (size_t)n * 128 + hd * 16);
        const float4* a1p = (const float4*)(a);
        const float4* a2p = (const float4*)(a + 16);
        float s1 = 0.f, s2 = 0.f;
#pragma unroll
        for (int i = 0; i < 4; ++i) {
            float4 xv = xp[i];
            float4 v1 = a1p[i];
            float4 v2 = a2p[i];
            s1 += xv.x * v1.x + xv.y * v1.y + xv.z * v1.z + xv.w * v1.w;
            s2 += xv.x * v2.x + xv.y * v2.y + xv.z * v2.z + xv.w * v2.w;
        }
        p1h[t] = __float2half_rn(s1);
        prh[(size_t)n * 16 + hd] = __float2half_rn(s2);
    } else {
        for (int i = tid; i < NBUCK; i += 1024) lh[i] = 0;
        __syncthreads();
        int base = (blockIdx.x - GPROJ) * EPB;
#pragma unroll
        for (int k = 0; k < EPB / 1024; ++k) {
            int e = base + k * 1024 + tid;
            if (e < N_EDGES) atomicAdd(&lh[(unsigned)edge[N_EDGES + e] >> BSHIFT], 1u);
        }
        __syncthreads();
        for (int i = tid; i < NBUCK; i += 1024)
            if (lh[i]) atomicAdd(&gcount[i], lh[i]);
    }
}

// Kernel 2: scatter 4-byte records (src<<7 | dst_local) into bucket order.
// Each block computes the bucket-offset scan locally (replaces the serial
// 1-block scan_kernel); block 0 publishes goff for denom_kernel.
__global__ __launch_bounds__(1024) void scatter_kernel(const int* __restrict__ edge,
                                                       const unsigned* __restrict__ gcount,
                                                       unsigned* __restrict__ gcur,
                                                       unsigned* __restrict__ goff,
                                                       unsigned* __restrict__ sorted) {
    __shared__ int lsrc[EPB];
    __shared__ int ldst[EPB];
    __shared__ unsigned lh[NBUCK];
    __shared__ unsigned lbase[NBUCK];
    __shared__ unsigned lgoff[NBUCK];
    __shared__ unsigned ls[1024];
    int t = threadIdx.x;
    int base = blockIdx.x * EPB;
    // in-block exclusive scan of global bucket counts
    unsigned v = (t < NBUCK) ? gcount[t] : 0u;
    ls[t] = v;
    for (int i = t; i < NBUCK; i += 1024) lh[i] = 0;
    __syncthreads();
    for (int d = 1; d < 1024; d <<= 1) {
        unsigned add = (t >= d) ? ls[t - d] : 0u;
        __syncthreads();
        ls[t] += add;
        __syncthreads();
    }
    if (t < NBUCK) lgoff[t] = ls[t] - v;
    if (blockIdx.x == 0 && t < NBUCK) {
        goff[t] = ls[t] - v;
        if (t == 0) goff[NBUCK] = N_EDGES;
    }
    __syncthreads();
#pragma unroll
    for (int k = 0; k < EPB / 1024; ++k) {
        int i = k * 1024 + t, e = base + i;
        if (e < N_EDGES) {
            lsrc[i] = edge[e];
            int d = edge[N_EDGES + e];
            ldst[i] = d;
            atomicAdd(&lh[(unsigned)d >> BSHIFT], 1u);
        }
    }
    __syncthreads();
    for (int i = t; i < NBUCK; i += 1024) {
        unsigned c = lh[i];
        lbase[i] = c ? lgoff[i] + atomicAdd(&gcur[i], c) : 0u;
        lh[i] = 0;   // reuse as local cursor
    }
    __syncthreads();
#pragma unroll
    for (int k = 0; k < EPB / 1024; ++k) {
        int i = k * 1024 + t, e = base + i;
        if (e < N_EDGES) {
            int d = ldst[i];
            unsigned b = (unsigned)d >> BSHIFT;
            unsigned pos = lbase[b] + atomicAdd(&lh[b], 1u);
            sorted[pos] = ((unsigned)lsrc[i] << BSHIFT) | (unsigned)(d & (BSIZE - 1));
        }
    }
}

// Kernel 3: one block per bucket, no float atomics. Counting-sort the bucket's
// records by dst_local in LDS; each thread owns (dl, head-pair) and serially
// accumulates its dst's edges in fp32 registers. Writes bf16 reciprocal
// denominators into the rd-half of prh.
__global__ __launch_bounds__(512) void denom_kernel(const unsigned* __restrict__ sorted,
                                                    const unsigned* __restrict__ goff,
                                                    const __half* __restrict__ p1h,
                                                    __half* __restrict__ prh) {
    __shared__ unsigned lsrc[CAP];     // 12 KB sorted-by-dl src indices
    __shared__ unsigned lh[BSIZE];     // per-dl count
    __shared__ unsigned lst[BSIZE];    // per-dl start
    __shared__ unsigned lcur[BSIZE];   // per-dl cursor
    __shared__ unsigned lscan[BSIZE];  // scan temp
    int t = threadIdx.x;
    int b = blockIdx.x;
    int dl = t >> 2;                   // 0..127: owned dst-local
    int hp = t & 3;                    // 0..3: owned head pair (2*hp, 2*hp+1)
    size_t node = (size_t)b * BSIZE + dl;
    bool valid = node < N_NODES;
    float p2a = 0.f, p2b = 0.f;
    if (valid) {
        float2 pv = __half22float2(*(const __half2*)(prh + node * 16 + hp * 2));
        p2a = pv.x; p2b = pv.y;
    }
    float acc0 = 0.f, acc1 = 0.f;
    unsigned s0 = goff[b], s1 = goff[b + 1];

    for (unsigned cs = s0; cs < s1; cs += CAP) {
        unsigned cnt = min((unsigned)CAP, s1 - cs);
        if (t < BSIZE) lh[t] = 0;
        __syncthreads();
        unsigned recs[RPT];
#pragma unroll
        for (int k = 0; k < RPT; ++k) {
            unsigned i = (unsigned)t + (unsigned)k * 512u;
            bool v = i < cnt;
            recs[k] = v ? sorted[cs + i] : 0xFFFFFFFFu;
            if (v) atomicAdd(&lh[recs[k] & (BSIZE - 1)], 1u);
        }
        __syncthreads();
        if (t < BSIZE) lscan[t] = lh[t];
        __syncthreads();
        for (int d = 1; d < BSIZE; d <<= 1) {
            unsigned v = 0;
            if (t < BSIZE && t >= d) v = lscan[t - d];
            __syncthreads();
            if (t < BSIZE) lscan[t] += v;
            __syncthreads();
        }
        if (t < BSIZE) {
            unsigned st = lscan[t] - lh[t];
            lst[t] = st;
            lcur[t] = st;
        }
        __syncthreads();
#pragma unroll
        for (int k = 0; k < RPT; ++k) {
            unsigned r = recs[k];
            if (r != 0xFFFFFFFFu) {
                unsigned d = r & (BSIZE - 1);
                unsigned pos = atomicAdd(&lcur[d], 1u);
                lsrc[pos] = r >> BSHIFT;
            }
        }
        __syncthreads();
        unsigned e0 = lst[dl], e1 = lst[dl] + lh[dl];
        for (unsigned k = e0; k < e1; ++k) {
            unsigned src = lsrc[k];                       // broadcast to 4 lanes
            float2 pv = __half22float2(*(const __half2*)(p1h + (size_t)src * 8 + hp * 2));
            acc0 += __expf(lrelu(pv.x + p2a));
            acc1 += __expf(lrelu(pv.y + p2b));
        }
        __syncthreads();   // protect lh/lst before next chunk
    }
    if (valid) {
        unsigned short r0 = f2bf(1.0f / (acc0 + 1e-16f));
        unsigned short r1 = f2bf(1.0f / (acc1 + 1e-16f));
        // rd-half of prh (4-byte aligned: byte offset node*32 + 16 + hp*4)
        *(unsigned*)((unsigned short*)prh + node * 16 + 8 + hp * 2) =
            ((unsigned)r1 << 16) | r0;
    }
}

// Kernel 4: edges in ORIGINAL order -> coalesced edge reads and out writes.
// Per edge: p1h[src] (16 B fp16) + prh[dst] (32 B, fp16 p2 + bf16 rd).
// Grid is exactly 6250 blocks (1.6M/256): no bounds check.
__global__ __launch_bounds__(256) void norm_kernel(const int* __restrict__ edge,
                                                   const __half* __restrict__ p1h,
                                                   const __half* __restrict__ prh,
                                                   float* __restrict__ out) {
    int e = blockIdx.x * 256 + threadIdx.x;
    int src = edge[e];
    int dst = edge[N_EDGES + e];
    float4 pv = *(const float4*)(p1h + (size_t)src * 8);       // 8 fp16 p1
    float4 qa = *(const float4*)(prh + (size_t)dst * 16);      // 8 fp16 p2
    float4 qb = *(const float4*)(prh + (size_t)dst * 16 + 8);  // 8 bf16 rd
    const __half2* s1p = (const __half2*)&pv;
    const __half2* s2p = (const __half2*)&qa;
    const unsigned short* rdu = (const unsigned short*)&qb;
    floatx4 o0, o1;
    float ov[8];
#pragma unroll
    for (int k = 0; k < 4; ++k) {
        float2 f1 = __half22float2(s1p[k]);
        float2 f2 = __half22float2(s2p[k]);
        ov[2 * k]     = __expf(lrelu(f1.x + f2.x)) * bf2f(rdu[2 * k]);
        ov[2 * k + 1] = __expf(lrelu(f1.y + f2.y)) * bf2f(rdu[2 * k + 1]);
    }
    o0.x = ov[0]; o0.y = ov[1]; o0.z = ov[2]; o0.w = ov[3];
    o1.x = ov[4]; o1.y = ov[5]; o1.z = ov[6]; o1.w = ov[7];
    floatx4* op = (floatx4*)(out + (size_t)e * 8);
    __builtin_nontemporal_store(o0, op);
    __builtin_nontemporal_store(o1, op + 1);
}

extern "C" void kernel_launch(void* const* d_in, const int* in_sizes, int n_in,
                              void* d_out, int out_size, void* d_ws, size_t ws_size,
                              hipStream_t stream) {
    const float* x    = (const float*)d_in[0];
    const float* a    = (const float*)d_in[1];
    const int*   edge = (const int*)d_in[2];
    float* out = (float*)d_out;

    // Workspace layout (~11.2 MB). gcount and gcur are ADJACENT so one
    // memset zeroes both.
    unsigned* sorted = (unsigned*)d_ws;                              // 6.4 MB
    __half*   p1h    = (__half*)(sorted + N_EDGES);                  // 1.6 MB
    __half*   prh    = p1h + NH;                                     // 3.2 MB (p2+rd)
    unsigned* gcount = (unsigned*)(prh + (size_t)N_NODES * 16);      // 782
    unsigned* gcur   = gcount + NBUCK;                               // 782
    unsigned* goff   = gcur + NBUCK;                                 // 783

    (void)hipMemsetAsync(gcount, 0, 2 * NBUCK * sizeof(unsigned), stream);

    proj_hist_kernel<<<GPROJ + NEB, 1024, 0, stream>>>(x, a, edge, p1h, prh, gcount);
    scatter_kernel<<<NEB, 1024, 0, stream>>>(edge, gcount, gcur, goff, sorted);
    denom_kernel<<<NBUCK, 512, 0, stream>>>(sorted, goff, p1h, prh);
    norm_kernel<<<N_EDGES / 256, 256, 0, stream>>>(edge, p1h, prh, out);
}

// Round 17
// 78.273 us; speedup vs baseline: 1.2801x; 1.1971x over previous
//
#include <hip/hip_runtime.h>
#include <hip/hip_bf16.h>
#include <hip/hip_fp16.h>

#define N_NODES 100000
#define N_EDGES 1600000
#define HEADS 8
#define NH (N_NODES * HEADS)    // 800000
#define ALPHA 0.2f

#define BSHIFT 7
#define BSIZE 128               // dst nodes per bucket
#define NBUCK 782               // ceil(100000 / 128)
#define EPB 4096                // edges per scatter block
#define NEB 391                 // ceil(1600000 / 4096)
#define GPROJ 782               // ceil(800000 / 1024) proj blocks (1024 thr)
#define CAP 3072                // fixed slots per bucket (mean 2046, max~2200 @ key=0)
#define RPT 6                   // CAP / 512 records per thread

typedef float floatx4 __attribute__((ext_vector_type(4)));

__device__ __forceinline__ float lrelu(float s) {
    return s >= 0.0f ? s : ALPHA * s;
}

// bf16 helpers (rd needs fp32 EXPONENT range: denom ~1e7 -> rd ~1e-7, which
// underflows fp16 subnormals -- the R12 failure -- but is a normal bf16).
__device__ __forceinline__ unsigned short f2bf(float f) {
    unsigned u = __float_as_uint(f);
    u += 0x7FFFu + ((u >> 16) & 1u);      // round-to-nearest-even
    return (unsigned short)(u >> 16);
}
__device__ __forceinline__ float bf2f(unsigned short s) {
    return __uint_as_float((unsigned)s << 16);
}

// Tables:
//   p1h[n*8+h]  : fp16 src-projection (range +-~16: fp16-safe)
//   prh[n*16+*] : 32-byte record = {fp16 p2[8] | bf16 rd[8]} -- one 32 B
//                 granule serves BOTH dst-indexed gathers in norm.
// R17: histogram/scan ELIMINATED -- sorted[] has a fixed CAP=3072-slot region
// per bucket; scatter allocates intra-bucket space via one global atomicAdd
// per (block, bucket) on gcur; denom reads counts from gcur. proj and scatter
// fused (independent roles by blockIdx).

// Kernel 1 (fused): blocks [0, GPROJ) project; blocks [GPROJ, +NEB) scatter
// 4-byte records (src<<7 | dst_local) into fixed-capacity bucket regions.
__global__ __launch_bounds__(1024) void proj_scatter_kernel(
        const float* __restrict__ x, const float* __restrict__ a,
        const int* __restrict__ edge,
        __half* __restrict__ p1h, __half* __restrict__ prh,
        unsigned* __restrict__ gcur, unsigned* __restrict__ sorted) {
    __shared__ int lsrc[EPB];
    __shared__ int ldst[EPB];
    __shared__ unsigned lh[NBUCK];
    __shared__ unsigned lbase[NBUCK];
    int tid = threadIdx.x;
    if (blockIdx.x < GPROJ) {
        int t = blockIdx.x * 1024 + tid;
        if (t >= NH) return;
        int hd = t & 7;
        int n  = t >> 3;
        const float4* xp  = (const float4*)(x + (size_t)n * 128 + hd * 16);
        const float4* a1p = (const float4*)(a);
        const float4* a2p = (const float4*)(a + 16);
        float s1 = 0.f, s2 = 0.f;
#pragma unroll
        for (int i = 0; i < 4; ++i) {
            float4 xv = xp[i];
            float4 v1 = a1p[i];
            float4 v2 = a2p[i];
            s1 += xv.x * v1.x + xv.y * v1.y + xv.z * v1.z + xv.w * v1.w;
            s2 += xv.x * v2.x + xv.y * v2.y + xv.z * v2.z + xv.w * v2.w;
        }
        p1h[t] = __float2half_rn(s1);
        prh[(size_t)n * 16 + hd] = __float2half_rn(s2);
    } else {
        int base = (blockIdx.x - GPROJ) * EPB;
        for (int i = tid; i < NBUCK; i += 1024) lh[i] = 0;
        __syncthreads();
#pragma unroll
        for (int k = 0; k < EPB / 1024; ++k) {
            int i = k * 1024 + tid, e = base + i;
            if (e < N_EDGES) {
                lsrc[i] = edge[e];
                int d = edge[N_EDGES + e];
                ldst[i] = d;
                atomicAdd(&lh[(unsigned)d >> BSHIFT], 1u);
            }
        }
        __syncthreads();
        for (int i = tid; i < NBUCK; i += 1024) {
            unsigned c = lh[i];
            lbase[i] = c ? (unsigned)i * CAP + atomicAdd(&gcur[i], c) : 0u;
            lh[i] = 0;   // reuse as local cursor
        }
        __syncthreads();
#pragma unroll
        for (int k = 0; k < EPB / 1024; ++k) {
            int i = k * 1024 + tid, e = base + i;
            if (e < N_EDGES) {
                int d = ldst[i];
                unsigned b = (unsigned)d >> BSHIFT;
                unsigned pos = lbase[b] + atomicAdd(&lh[b], 1u);
                sorted[pos] = ((unsigned)lsrc[i] << BSHIFT) | (unsigned)(d & (BSIZE - 1));
            }
        }
    }
}

// Kernel 2: one block per bucket, no float atomics. Counting-sort the bucket's
// records by dst_local in LDS (single chunk: region capacity == CAP); each
// thread owns (dl, head-pair) and serially accumulates its dst's edges in
// fp32 registers. Writes bf16 reciprocal denominators into prh's rd-half.
__global__ __launch_bounds__(512) void denom_kernel(const unsigned* __restrict__ sorted,
                                                    const unsigned* __restrict__ gcur,
                                                    const __half* __restrict__ p1h,
                                                    __half* __restrict__ prh) {
    __shared__ unsigned lsrc[CAP];     // 12 KB sorted-by-dl src indices
    __shared__ unsigned lh[BSIZE];     // per-dl count
    __shared__ unsigned lst[BSIZE];    // per-dl start
    __shared__ unsigned lcur[BSIZE];   // per-dl cursor
    __shared__ unsigned lscan[BSIZE];  // scan temp
    int t = threadIdx.x;
    int b = blockIdx.x;
    int dl = t >> 2;                   // 0..127: owned dst-local
    int hp = t & 3;                    // 0..3: owned head pair (2*hp, 2*hp+1)
    size_t node = (size_t)b * BSIZE + dl;
    bool valid = node < N_NODES;
    float p2a = 0.f, p2b = 0.f;
    if (valid) {
        float2 pv = __half22float2(*(const __half2*)(prh + node * 16 + hp * 2));
        p2a = pv.x; p2b = pv.y;
    }
    unsigned cs  = (unsigned)b * CAP;
    unsigned cnt = min(gcur[b], (unsigned)CAP);

    if (t < BSIZE) lh[t] = 0;
    __syncthreads();
    unsigned recs[RPT];
#pragma unroll
    for (int k = 0; k < RPT; ++k) {
        unsigned i = (unsigned)t + (unsigned)k * 512u;
        bool v = i < cnt;
        recs[k] = v ? sorted[cs + i] : 0xFFFFFFFFu;
        if (v) atomicAdd(&lh[recs[k] & (BSIZE - 1)], 1u);
    }
    __syncthreads();
    if (t < BSIZE) lscan[t] = lh[t];
    __syncthreads();
    for (int d = 1; d < BSIZE; d <<= 1) {
        unsigned v = 0;
        if (t < BSIZE && t >= d) v = lscan[t - d];
        __syncthreads();
        if (t < BSIZE) lscan[t] += v;
        __syncthreads();
    }
    if (t < BSIZE) {
        unsigned st = lscan[t] - lh[t];
        lst[t] = st;
        lcur[t] = st;
    }
    __syncthreads();
#pragma unroll
    for (int k = 0; k < RPT; ++k) {
        unsigned r = recs[k];
        if (r != 0xFFFFFFFFu) {
            unsigned d = r & (BSIZE - 1);
            unsigned pos = atomicAdd(&lcur[d], 1u);
            lsrc[pos] = r >> BSHIFT;
        }
    }
    __syncthreads();
    float acc0 = 0.f, acc1 = 0.f;
    unsigned e0 = lst[dl], e1 = lst[dl] + lh[dl];
    for (unsigned k = e0; k < e1; ++k) {
        unsigned src = lsrc[k];                       // broadcast to 4 lanes
        float2 pv = __half22float2(*(const __half2*)(p1h + (size_t)src * 8 + hp * 2));
        acc0 += __expf(lrelu(pv.x + p2a));
        acc1 += __expf(lrelu(pv.y + p2b));
    }
    if (valid) {
        unsigned short r0 = f2bf(1.0f / (acc0 + 1e-16f));
        unsigned short r1 = f2bf(1.0f / (acc1 + 1e-16f));
        // rd-half of prh (4-byte aligned: byte offset node*32 + 16 + hp*4)
        *(unsigned*)((unsigned short*)prh + node * 16 + 8 + hp * 2) =
            ((unsigned)r1 << 16) | r0;
    }
}

// Kernel 3: edges in ORIGINAL order -> coalesced edge reads and out writes.
// Per edge: p1h[src] (16 B fp16) + prh[dst] (32 B, fp16 p2 + bf16 rd).
// Grid is exactly 6250 blocks (1.6M/256): no bounds check.
__global__ __launch_bounds__(256) void norm_kernel(const int* __restrict__ edge,
                                                   const __half* __restrict__ p1h,
                                                   const __half* __restrict__ prh,
                                                   float* __restrict__ out) {
    int e = blockIdx.x * 256 + threadIdx.x;
    int src = edge[e];
    int dst = edge[N_EDGES + e];
    float4 pv = *(const float4*)(p1h + (size_t)src * 8);       // 8 fp16 p1
    float4 qa = *(const float4*)(prh + (size_t)dst * 16);      // 8 fp16 p2
    float4 qb = *(const float4*)(prh + (size_t)dst * 16 + 8);  // 8 bf16 rd
    const __half2* s1p = (const __half2*)&pv;
    const __half2* s2p = (const __half2*)&qa;
    const unsigned short* rdu = (const unsigned short*)&qb;
    floatx4 o0, o1;
    float ov[8];
#pragma unroll
    for (int k = 0; k < 4; ++k) {
        float2 f1 = __half22float2(s1p[k]);
        float2 f2 = __half22float2(s2p[k]);
        ov[2 * k]     = __expf(lrelu(f1.x + f2.x)) * bf2f(rdu[2 * k]);
        ov[2 * k + 1] = __expf(lrelu(f1.y + f2.y)) * bf2f(rdu[2 * k + 1]);
    }
    o0.x = ov[0]; o0.y = ov[1]; o0.z = ov[2]; o0.w = ov[3];
    o1.x = ov[4]; o1.y = ov[5]; o1.z = ov[6]; o1.w = ov[7];
    floatx4* op = (floatx4*)(out + (size_t)e * 8);
    __builtin_nontemporal_store(o0, op);
    __builtin_nontemporal_store(o1, op + 1);
}

extern "C" void kernel_launch(void* const* d_in, const int* in_sizes, int n_in,
                              void* d_out, int out_size, void* d_ws, size_t ws_size,
                              hipStream_t stream) {
    const float* x    = (const float*)d_in[0];
    const float* a    = (const float*)d_in[1];
    const int*   edge = (const int*)d_in[2];
    float* out = (float*)d_out;

    // Workspace layout (~14.5 MB):
    unsigned* sorted = (unsigned*)d_ws;                              // 9.6 MB (NBUCK*CAP)
    __half*   p1h    = (__half*)(sorted + (size_t)NBUCK * CAP);      // 1.6 MB
    __half*   prh    = p1h + NH;                                     // 3.2 MB (p2+rd)
    unsigned* gcur   = (unsigned*)(prh + (size_t)N_NODES * 16);      // 782

    (void)hipMemsetAsync(gcur, 0, NBUCK * sizeof(unsigned), stream);

    proj_scatter_kernel<<<GPROJ + NEB, 1024, 0, stream>>>(x, a, edge, p1h, prh,
                                                          gcur, sorted);
    denom_kernel<<<NBUCK, 512, 0, stream>>>(sorted, gcur, p1h, prh);
    norm_kernel<<<N_EDGES / 256, 256, 0, stream>>>(edge, p1h, prh, out);
}